// Round 2
// baseline (253.849 us; speedup 1.0000x reference)
//
#include <hip/hip_runtime.h>
#include <math.h>

#define NROWS 4096
#define DIN   1024
#define DOUT  256
#define NPAIR 528        // 32*33/2 triangular 128x128 block pairs
#define GRID  512        // 2 blocks/CU x 256 CUs -> all co-resident

using bfrag = __attribute__((ext_vector_type(8))) short;  // 8 bf16 (4 VGPRs)
using ffrag = __attribute__((ext_vector_type(4))) float;  // 4 fp32 acc

// Fragment-order layouts (mfma_f32_16x16x32_bf16; A and B share the per-lane
// map: elem[lane l][j] = M[tile*16 + (l&15)][ks*32 + (l>>4)*8 + j]):
//   Ws: frag f = (nt*32 + ks)*64 + l     nt<16 (W col-tiles), ks<32
//   hs: frag f = (t*8  + ks)*64 + l      t<256 (h row-tiles), ks<8  (K=256)

static __device__ __forceinline__ unsigned short f2bf(float f) {
    unsigned int u = __float_as_uint(f);
    u = (u + 0x7fffu + ((u >> 16) & 1u)) >> 16;
    return (unsigned short)u;
}
static __device__ __forceinline__ unsigned int pack2(float lo, float hi) {
    return (unsigned int)f2bf(lo) | ((unsigned int)f2bf(hi) << 16);
}
// order-preserving float<->uint key (unsigned compare == float compare)
static __device__ __forceinline__ unsigned int fkey(float f) {
    unsigned int b = __float_as_uint(f);
    return (b & 0x80000000u) ? ~b : (b | 0x80000000u);
}
static __device__ __forceinline__ float funkey(unsigned int u) {
    return __uint_as_float((u & 0x80000000u) ? (u & 0x7fffffffu) : ~u);
}

// Manual grid barrier: all GRID blocks are co-resident (launch_bounds(256,2),
// 43KB LDS/block -> 2 blocks/CU guaranteed; sole kernel on the GPU).
// Monotonic counter; arrival = agent-scope ACQ_REL add (releases this block's
// prior stores via L2 writeback), spin = agent-scope ACQUIRE load (invalidates
// L1/L2 so post-barrier plain loads see remote writes). __syncthreads fences
// the rest of the block on both sides.
static __device__ __forceinline__ void gridbar(unsigned int* bar, unsigned int target) {
    __syncthreads();
    if (threadIdx.x == 0) {
        __hip_atomic_fetch_add(bar, 1u, __ATOMIC_ACQ_REL, __HIP_MEMORY_SCOPE_AGENT);
        while (__hip_atomic_load(bar, __ATOMIC_ACQUIRE, __HIP_MEMORY_SCOPE_AGENT) < target)
            __builtin_amdgcn_s_sleep(1);
    }
    __syncthreads();
}

// ---------------------------------------------------------------------------
// One fused kernel (normal launch, graph-capturable), 4 phases:
//   A: Ws fragment gather + sq/key/out init          (64 frags/block, wave 0)
//   B: h = x@W + b -> hs frags + row-sq              (512 half-tiles, all busy)
//   C: triangular Gram + hardest pos/neg atomics     (528 pairs, grid-stride)
//   D: decode keys, per-row loss, sum -> out[0]      (blocks 0..15)
// ---------------------------------------------------------------------------
__global__ __launch_bounds__(256, 2) void fused(
    const float* __restrict__ x, const float* __restrict__ W,
    const float* __restrict__ bv, const int* __restrict__ targets,
    unsigned short* __restrict__ Ws, unsigned short* __restrict__ hs,
    float* __restrict__ sq, unsigned int* __restrict__ pmaxk,
    unsigned int* __restrict__ pmink, unsigned int* __restrict__ bar,
    float* __restrict__ out) {
    __shared__ __align__(16) short Axs[32 * 528];   // 33792 B frag-order A strip
    __shared__ __align__(16) short T[8][16][36];    // 9216 B C transpose (8 nt)
    __shared__ float wsum[4];

    const int tid = threadIdx.x;
    const int bid = blockIdx.x;
    const int w   = tid >> 6;          // wave 0..3
    const int l   = tid & 63;
    const int m16 = l & 15;
    const int q   = l >> 4;

    // ---------------- Phase A: Ws gather + init ----------------
    if (tid < 64) {
        const int f  = bid * 64 + tid;               // 512*64 = 32768 Ws frags
        const int ks = (f >> 6) & 31;
        const int nt = f >> 11;
        const int col = nt * 16 + m16;
        const int k0  = ks * 32 + q * 8;
        float a[8];
#pragma unroll
        for (int j = 0; j < 8; ++j) a[j] = W[(size_t)(k0 + j) * DOUT + col];
        uint4 v;
        v.x = pack2(a[0], a[1]);
        v.y = pack2(a[2], a[3]);
        v.z = pack2(a[4], a[5]);
        v.w = pack2(a[6], a[7]);
        *(uint4*)&Ws[(size_t)f * 8] = v;
    } else if (tid < 72) {
        const int i = bid * 8 + (tid - 64);          // 512*8 = 4096 rows
        sq[i]    = 0.0f;
        pmaxk[i] = 0u;            // < any real key
        pmink[i] = 0xFFFFFFFFu;   // > any real key
    } else if (tid == 72 && bid == 0) {
        *out = 0.0f;
    }
    gridbar(bar, GRID);

    // ---------------- Phase B: h = x@W + b ----------------
    // block = half-tile: row-tile t = bid>>1 (16 rows), nt range [half*8, half*8+8)
    {
        const int t    = bid >> 1;
        const int half = bid & 1;

        // stage 16x1024 fp32 strip -> bf16 frag-order LDS (wave w: rows 4w..4w+3)
#pragma unroll
        for (int rr = 0; rr < 4; ++rr) {
            const int row = w * 4 + rr;
            const float* xrow = x + (size_t)(t * 16 + row) * DIN;
#pragma unroll
            for (int s = 0; s < 2; ++s) {
                const int c = s * 512 + l * 8;
                const float4 p0 = *(const float4*)(xrow + c);
                const float4 p1 = *(const float4*)(xrow + c + 4);
                uint4 v;
                v.x = pack2(p0.x, p0.y);
                v.y = pack2(p0.z, p0.w);
                v.z = pack2(p1.x, p1.y);
                v.w = pack2(p1.z, p1.w);
                const int ks = c >> 5;
                const int lw = ((c >> 3) & 3) * 16 + row;
                *(uint4*)&Axs[ks * 528 + lw * 8] = v;
            }
        }
        __syncthreads();

        // K-loop: wave w computes nt0 = half*8 + 2w and nt0+1
        const int nt0 = half * 8 + w * 2;
        const bfrag* B0 = (const bfrag*)Ws + ((size_t)nt0 * 32) * 64 + l;
        ffrag acc0 = {};
        ffrag acc1 = {};
#pragma unroll
        for (int ks = 0; ks < 32; ++ks) {
            const bfrag a = *(const bfrag*)&Axs[ks * 528 + l * 8];
            acc0 = __builtin_amdgcn_mfma_f32_16x16x32_bf16(a, B0[ks * 64], acc0, 0, 0, 0);
            acc1 = __builtin_amdgcn_mfma_f32_16x16x32_bf16(a, B0[2048 + ks * 64], acc1, 0, 0, 0);
        }

        // epilogue: bias, T transpose, row-sq partial over this wave's 32 features
        float pr[4];
        {
            const float bc0 = bv[nt0 * 16 + m16];
            const float bc1 = bv[(nt0 + 1) * 16 + m16];
#pragma unroll
            for (int reg = 0; reg < 4; ++reg) {
                const float h0 = acc0[reg] + bc0;
                const float h1 = acc1[reg] + bc1;
                pr[reg] = h0 * h0 + h1 * h1;
                T[w * 2][q * 4 + reg][m16]     = f2bf(h0);
                T[w * 2 + 1][q * 4 + reg][m16] = f2bf(h1);
            }
        }
#pragma unroll
        for (int reg = 0; reg < 4; ++reg) {
            float pp = pr[reg];
#pragma unroll
            for (int mask = 1; mask < 16; mask <<= 1) pp += __shfl_xor(pp, mask);
            if (m16 == 0) atomicAdd(&sq[t * 16 + q * 4 + reg], pp);
        }
        __syncthreads();

        // emit hs frags for ks = half*4 .. half*4+3 (256 threads = 4 frag-sets)
        {
            const int ksl = tid >> 6;              // 0..3
            const int ks  = half * 4 + ksl;
            const int qq  = l >> 4;
            bfrag v = *(const bfrag*)&T[2 * ksl + (qq >> 1)][l & 15][(qq & 1) * 8];
            ((bfrag*)hs)[((size_t)t * 8 + ks) * 64 + l] = v;   // 1KB/wave store
        }
    }
    gridbar(bar, 2 * GRID);

    // ---------------- Phase C: triangular Gram + hardest pos/neg ----------------
    for (int k = bid; k < NPAIR; k += GRID) {
        const int wi = w & 1, wj = w >> 1;

        // decode triangular pair index k -> (bi <= bj)
        int bj = (int)((sqrtf(8.0f * (float)k + 1.0f) - 1.0f) * 0.5f);
        while ((bj + 1) * (bj + 2) / 2 <= k) ++bj;
        while (bj * (bj + 1) / 2 > k) --bj;
        const int bi = k - bj * (bj + 1) / 2;
        const bool diag = (bi == bj);

        const int iw = bi * 128 + wi * 64;
        const int jw = bj * 128 + wj * 64;
        const int tA = iw >> 4;
        const int tB = jw >> 4;

        ffrag acc[4][4] = {};                        // [mi][nj]

#pragma unroll
        for (int ks = 0; ks < 8; ++ks) {
            bfrag a[4], bb[4];
#pragma unroll
            for (int mi = 0; mi < 4; ++mi)
                a[mi] = *(const bfrag*)&hs[(((size_t)(tA + mi) * 8 + ks) * 64 + l) * 8];
#pragma unroll
            for (int nj = 0; nj < 4; ++nj)
                bb[nj] = *(const bfrag*)&hs[(((size_t)(tB + nj) * 8 + ks) * 64 + l) * 8];
#pragma unroll
            for (int mi = 0; mi < 4; ++mi)
#pragma unroll
                for (int nj = 0; nj < 4; ++nj)
                    acc[mi][nj] = __builtin_amdgcn_mfma_f32_16x16x32_bf16(
                        a[mi], bb[nj], acc[mi][nj], 0, 0, 0);
        }

        // fused epilogue, both directions
        int   tj[4];
        float svj[4];
#pragma unroll
        for (int nj = 0; nj < 4; ++nj) {
            const int col = jw + nj * 16 + m16;
            tj[nj]  = targets[col];
            svj[nj] = sq[col];
        }

        float cmx[4], cmn[4];
#pragma unroll
        for (int nj = 0; nj < 4; ++nj) { cmx[nj] = -INFINITY; cmn[nj] = INFINITY; }

#pragma unroll
        for (int mi = 0; mi < 4; ++mi)
#pragma unroll
            for (int reg = 0; reg < 4; ++reg) {
                const int row = iw + mi * 16 + q * 4 + reg;
                const int ti  = targets[row];
                const float si = sq[row];
                float mx = -INFINITY, mn = INFINITY;
#pragma unroll
                for (int nj = 0; nj < 4; ++nj) {
                    const float g    = acc[mi][nj][reg];
                    const float vrow = fmaf(-2.0f, g, svj[nj]);
                    const float vcol = fmaf(-2.0f, g, si);
                    if (tj[nj] == ti) {
                        mx = fmaxf(mx, vrow);
                        cmx[nj] = fmaxf(cmx[nj], vcol);
                    } else {
                        mn = fminf(mn, vrow);
                        cmn[nj] = fminf(cmn[nj], vcol);
                    }
                }
                // row-side: reduce over the 16 m16-lanes, then one atomic pair
#pragma unroll
                for (int mask = 1; mask < 16; mask <<= 1) {
                    mx = fmaxf(mx, __shfl_xor(mx, mask));
                    mn = fminf(mn, __shfl_xor(mn, mask));
                }
                if (m16 == 0) {
                    atomicMax(&pmaxk[row], fkey(mx));
                    atomicMin(&pmink[row], fkey(mn));
                }
            }

        // col-side: reduce over the q bits (lanes 16,32 apart), skip on diagonal
        if (!diag) {
#pragma unroll
            for (int nj = 0; nj < 4; ++nj) {
                float mx = cmx[nj], mn = cmn[nj];
                mx = fmaxf(mx, __shfl_xor(mx, 16));
                mn = fminf(mn, __shfl_xor(mn, 16));
                mx = fmaxf(mx, __shfl_xor(mx, 32));
                mn = fminf(mn, __shfl_xor(mn, 32));
                if (q == 0) {
                    const int col = jw + nj * 16 + m16;
                    atomicMax(&pmaxk[col], fkey(mx));
                    atomicMin(&pmink[col], fkey(mn));
                }
            }
        }
    }
    gridbar(bar, 3 * GRID);

    // ---------------- Phase D: finalize ----------------
    if (bid < NROWS / 256) {
        const int i = bid * 256 + tid;
        const float mp = funkey(pmaxk[i]);
        const float mn = funkey(pmink[i]);
        const float si = sq[i];
        const float hp = sqrtf(fmaxf(si + mp, 0.0f));
        const float hn = sqrtf(fmaxf(si + mn, 0.0f));
        const float d  = hp - hn;
        float li = fmaxf(d, 0.0f) + log1pf(expf(-fabsf(d)));  // stable log1p(exp(d))
#pragma unroll
        for (int off = 32; off; off >>= 1) li += __shfl_down(li, off);
        if (l == 0) wsum[w] = li;
        __syncthreads();
        if (tid == 0)
            atomicAdd(out, wsum[0] + wsum[1] + wsum[2] + wsum[3]);
    }
}

// ---------------------------------------------------------------------------
extern "C" void kernel_launch(void* const* d_in, const int* in_sizes, int n_in,
                              void* d_out, int out_size, void* d_ws, size_t ws_size,
                              hipStream_t stream) {
    const float* x       = (const float*)d_in[0];
    const float* W       = (const float*)d_in[1];
    const float* bv      = (const float*)d_in[2];
    const int*   targets = (const int*)d_in[3];
    float* out = (float*)d_out;

    unsigned short* Ws    = (unsigned short*)d_ws;              // 256*1024 bf16 (frag order)
    unsigned short* hs    = Ws + DOUT * DIN;                    // 4096*256 bf16 (frag order)
    float*          sq    = (float*)(hs + NROWS * DOUT);        // 4096
    unsigned int*   pmaxk = (unsigned int*)(sq + NROWS);        // 4096 keys
    unsigned int*   pmink = pmaxk + NROWS;                      // 4096 keys
    unsigned int*   bar   = pmink + NROWS;                      // grid barrier counter

    hipMemsetAsync(bar, 0, 16, stream);   // reset barrier each replay (captured)
    fused<<<GRID, 256, 0, stream>>>(x, W, bv, targets, Ws, hs, sq,
                                    pmaxk, pmink, bar, out);
}

// Round 3
// 99.766 us; speedup vs baseline: 2.5445x; 2.5445x over previous
//
#include <hip/hip_runtime.h>
#include <math.h>

#define NROWS 4096
#define DIN   1024
#define DOUT  256
#define NPAIR 528        // 32*33/2 triangular 128x128 block pairs

using bfrag = __attribute__((ext_vector_type(8))) short;  // 8 bf16 (4 VGPRs)
using ffrag = __attribute__((ext_vector_type(4))) float;  // 4 fp32 acc

// Fragment-order layouts (mfma_f32_16x16x32_bf16; A and B share the per-lane
// map: elem[lane l][j] = M[tile*16 + (l&15)][ks*32 + (l>>4)*8 + j]):
//   Ws: frag f = (nt*32 + ks)*64 + l     nt<16 (W col-tiles), ks<32
//   hs: frag f = (t*8  + ks)*64 + l      t<256 (h row-tiles), ks<8  (K=256)

static __device__ __forceinline__ unsigned short f2bf(float f) {
    unsigned int u = __float_as_uint(f);
    u = (u + 0x7fffu + ((u >> 16) & 1u)) >> 16;
    return (unsigned short)u;
}
static __device__ __forceinline__ unsigned int pack2(float lo, float hi) {
    return (unsigned int)f2bf(lo) | ((unsigned int)f2bf(hi) << 16);
}
// order-preserving float<->uint key (unsigned compare == float compare)
static __device__ __forceinline__ unsigned int fkey(float f) {
    unsigned int b = __float_as_uint(f);
    return (b & 0x80000000u) ? ~b : (b | 0x80000000u);
}
static __device__ __forceinline__ float funkey(unsigned int u) {
    return __uint_as_float((u & 0x80000000u) ? (u & 0x7fffffffu) : ~u);
}

// ---------------------------------------------------------------------------
// Kernel 0 (setup): Ws fragment gather + sq/out/key-slot init. 128 blocks.
// ---------------------------------------------------------------------------
__global__ __launch_bounds__(256) void setup(const float* __restrict__ W,
                                             unsigned short* __restrict__ Ws,
                                             float* __restrict__ sq,
                                             unsigned int* __restrict__ pmaxk,
                                             unsigned int* __restrict__ pmink,
                                             float* __restrict__ out) {
    const int f = blockIdx.x * 256 + threadIdx.x;    // 32768 Ws frags
    {
        const int l  = f & 63;
        const int ks = (f >> 6) & 31;
        const int nt = f >> 11;
        const int col = nt * 16 + (l & 15);
        const int k0  = ks * 32 + (l >> 4) * 8;
        float a[8];
#pragma unroll
        for (int j = 0; j < 8; ++j) a[j] = W[(size_t)(k0 + j) * DOUT + col];
        uint4 v;
        v.x = pack2(a[0], a[1]);
        v.y = pack2(a[2], a[3]);
        v.z = pack2(a[4], a[5]);
        v.w = pack2(a[6], a[7]);
        *(uint4*)&Ws[(size_t)f * 8] = v;
    }
    if (f < NROWS) {
        sq[f]    = 0.0f;
        pmaxk[f] = 0u;            // < any real key
        pmink[f] = 0xFFFFFFFFu;   // > any real key
    }
    if (f == 0) *out = 0.0f;
}

// ---------------------------------------------------------------------------
// Kernel 1: h = x@W + b. 256 blocks x 1024 threads (16 waves = 16 nt tiles),
// 2 blocks/CU -> 32 waves/CU for latency hiding after the ws poison sweep.
// Stage: 16x1024 fp32 coalesced (each wave one 2KB row run) -> bf16
// frag-order LDS. Wave w: nt = w: 32 ks x (1 LDS A-frag + 1 Ws frag + MFMA).
// Epilogue: bias, row-sq atomicAdd, cross-wave T transpose -> hs (barrier).
// ---------------------------------------------------------------------------
__global__ __launch_bounds__(1024) void gemm1_direct(
    const float* __restrict__ x, const unsigned short* __restrict__ Ws,
    const float* __restrict__ b,
    unsigned short* __restrict__ hs, float* __restrict__ sq) {
    __shared__ __align__(16) short Axs[32 * 528];    // 33792 B frag-order A strip
    __shared__ __align__(16) short T[16][16][36];    // 18432 B C transpose

    const int tid = threadIdx.x;
    const int w   = tid >> 6;            // wave 0..15 = nt tile
    const int l   = tid & 63;
    const int m16 = l & 15;
    const int q   = l >> 4;
    const int t   = blockIdx.x;          // x row-tile (0..255)

    // ---- stage x strip (wave w loads row w, fully coalesced) ----
    const float* xrow = x + (size_t)(t * 16 + w) * DIN;
#pragma unroll
    for (int s = 0; s < 2; ++s) {
        const int c = s * 512 + l * 8;
        const float4 p0 = *(const float4*)(xrow + c);
        const float4 p1 = *(const float4*)(xrow + c + 4);
        uint4 v;
        v.x = pack2(p0.x, p0.y);
        v.y = pack2(p0.z, p0.w);
        v.z = pack2(p1.x, p1.y);
        v.w = pack2(p1.z, p1.w);
        const int ks = c >> 5;
        const int lw = ((c >> 3) & 3) * 16 + w;
        *(uint4*)&Axs[ks * 528 + lw * 8] = v;
    }
    __syncthreads();

    // ---- K-loop: one nt tile per wave ----
    const bfrag* B = (const bfrag*)Ws + ((size_t)w * 32) * 64 + l;
    ffrag acc = {};
#pragma unroll
    for (int ks = 0; ks < 32; ++ks) {
        const bfrag a = *(const bfrag*)&Axs[ks * 528 + l * 8];
        acc = __builtin_amdgcn_mfma_f32_16x16x32_bf16(a, B[ks * 64], acc, 0, 0, 0);
    }

    // ---- epilogue ----
    const float bc = b[w * 16 + m16];
    float hv[4];
#pragma unroll
    for (int reg = 0; reg < 4; ++reg) hv[reg] = acc[reg] + bc;

    // row-sq partial over this wave's 16 features
#pragma unroll
    for (int reg = 0; reg < 4; ++reg) {
        float p = hv[reg] * hv[reg];
#pragma unroll
        for (int mask = 1; mask < 16; mask <<= 1) p += __shfl_xor(p, mask);
        if (m16 == 0) atomicAdd(&sq[t * 16 + q * 4 + reg], p);
    }

    // T[w][row][col16] = h[t*16+row][w*16+col16]
#pragma unroll
    for (int reg = 0; reg < 4; ++reg)
        T[w][q * 4 + reg][m16] = f2bf(hv[reg]);
    __syncthreads();

    // emit hs frags: feature ks*32 + q*8 + j = T[2ks + (q>>1)][m16][(q&1)*8+j]
    if (tid < 512) {
        const int ks = tid >> 6;
        const int ll = tid & 63;
        const int qq = ll >> 4;
        bfrag v = *(const bfrag*)&T[2 * ks + (qq >> 1)][ll & 15][(qq & 1) * 8];
        ((bfrag*)hs)[((size_t)t * 8 + ks) * 64 + ll] = v;   // 1KB/wave store
    }
}

// ---------------------------------------------------------------------------
// Kernel 2: triangular register-direct Gram; results accumulate via global
// atomic max/min on order-preserving uint keys (no partial arrays).
// ---------------------------------------------------------------------------
__global__ __launch_bounds__(256) void hardest_tri(
    const unsigned short* __restrict__ hs, const float* __restrict__ sq,
    const int* __restrict__ targets,
    unsigned int* __restrict__ pmaxk, unsigned int* __restrict__ pmink) {
    const int tid = threadIdx.x;
    const int w   = tid >> 6;
    const int wi  = w & 1, wj = w >> 1;
    const int l   = tid & 63;
    const int m16 = l & 15;
    const int q   = l >> 4;

    // decode triangular pair index k -> (bi <= bj)
    const int k = blockIdx.x;
    int bj = (int)((sqrtf(8.0f * (float)k + 1.0f) - 1.0f) * 0.5f);
    while ((bj + 1) * (bj + 2) / 2 <= k) ++bj;
    while (bj * (bj + 1) / 2 > k) --bj;
    const int bi = k - bj * (bj + 1) / 2;
    const bool diag = (bi == bj);

    const int iw = bi * 128 + wi * 64;
    const int jw = bj * 128 + wj * 64;
    const int tA = iw >> 4;
    const int tB = jw >> 4;

    ffrag acc[4][4] = {};                        // [mi][nj]

#pragma unroll
    for (int ks = 0; ks < 8; ++ks) {
        bfrag a[4], bb[4];
#pragma unroll
        for (int mi = 0; mi < 4; ++mi)
            a[mi] = *(const bfrag*)&hs[(((size_t)(tA + mi) * 8 + ks) * 64 + l) * 8];
#pragma unroll
        for (int nj = 0; nj < 4; ++nj)
            bb[nj] = *(const bfrag*)&hs[(((size_t)(tB + nj) * 8 + ks) * 64 + l) * 8];
#pragma unroll
        for (int mi = 0; mi < 4; ++mi)
#pragma unroll
            for (int nj = 0; nj < 4; ++nj)
                acc[mi][nj] = __builtin_amdgcn_mfma_f32_16x16x32_bf16(
                    a[mi], bb[nj], acc[mi][nj], 0, 0, 0);
    }

    // ---- fused epilogue, both directions ----
    int   tj[4];
    float svj[4];
#pragma unroll
    for (int nj = 0; nj < 4; ++nj) {
        const int col = jw + nj * 16 + m16;
        tj[nj]  = targets[col];
        svj[nj] = sq[col];
    }

    float cmx[4], cmn[4];
#pragma unroll
    for (int nj = 0; nj < 4; ++nj) { cmx[nj] = -INFINITY; cmn[nj] = INFINITY; }

#pragma unroll
    for (int mi = 0; mi < 4; ++mi)
#pragma unroll
        for (int reg = 0; reg < 4; ++reg) {
            const int row = iw + mi * 16 + q * 4 + reg;
            const int ti  = targets[row];
            const float si = sq[row];
            float mx = -INFINITY, mn = INFINITY;
#pragma unroll
            for (int nj = 0; nj < 4; ++nj) {
                const float g    = acc[mi][nj][reg];
                const float vrow = fmaf(-2.0f, g, svj[nj]);
                const float vcol = fmaf(-2.0f, g, si);
                if (tj[nj] == ti) {
                    mx = fmaxf(mx, vrow);
                    cmx[nj] = fmaxf(cmx[nj], vcol);
                } else {
                    mn = fminf(mn, vrow);
                    cmn[nj] = fminf(cmn[nj], vcol);
                }
            }
            // row-side: reduce over the 16 m16-lanes, then one atomic pair
#pragma unroll
            for (int mask = 1; mask < 16; mask <<= 1) {
                mx = fmaxf(mx, __shfl_xor(mx, mask));
                mn = fminf(mn, __shfl_xor(mn, mask));
            }
            if (m16 == 0) {
                atomicMax(&pmaxk[row], fkey(mx));
                atomicMin(&pmink[row], fkey(mn));
            }
        }

    // col-side: reduce over the q bits (lanes 16,32 apart), skip on diagonal
    if (!diag) {
#pragma unroll
        for (int nj = 0; nj < 4; ++nj) {
            float mx = cmx[nj], mn = cmn[nj];
            mx = fmaxf(mx, __shfl_xor(mx, 16));
            mn = fminf(mn, __shfl_xor(mn, 16));
            mx = fmaxf(mx, __shfl_xor(mx, 32));
            mn = fminf(mn, __shfl_xor(mn, 32));
            if (q == 0) {
                const int col = jw + nj * 16 + m16;
                atomicMax(&pmaxk[col], fkey(mx));
                atomicMin(&pmink[col], fkey(mn));
            }
        }
    }
}

// ---------------------------------------------------------------------------
// Kernel 3: decode keys, per-row loss, sum -> out[0]. 16 blocks.
// ---------------------------------------------------------------------------
__global__ __launch_bounds__(256) void finalize(const float* __restrict__ sq,
                                                const unsigned int* __restrict__ pmaxk,
                                                const unsigned int* __restrict__ pmink,
                                                float* __restrict__ out) {
    __shared__ float wsum[4];
    const int i = blockIdx.x * 256 + threadIdx.x;
    const float mp = funkey(pmaxk[i]);
    const float mn = funkey(pmink[i]);
    const float si = sq[i];
    const float hp = sqrtf(fmaxf(si + mp, 0.0f));
    const float hn = sqrtf(fmaxf(si + mn, 0.0f));
    const float d  = hp - hn;
    float li = fmaxf(d, 0.0f) + log1pf(expf(-fabsf(d)));  // stable log1p(exp(d))
#pragma unroll
    for (int off = 32; off; off >>= 1) li += __shfl_down(li, off);
    const int lane = threadIdx.x & 63, wv = threadIdx.x >> 6;
    if (lane == 0) wsum[wv] = li;
    __syncthreads();
    if (threadIdx.x == 0)
        atomicAdd(out, wsum[0] + wsum[1] + wsum[2] + wsum[3]);
}

// ---------------------------------------------------------------------------
extern "C" void kernel_launch(void* const* d_in, const int* in_sizes, int n_in,
                              void* d_out, int out_size, void* d_ws, size_t ws_size,
                              hipStream_t stream) {
    const float* x       = (const float*)d_in[0];
    const float* W       = (const float*)d_in[1];
    const float* b       = (const float*)d_in[2];
    const int*   targets = (const int*)d_in[3];
    float* out = (float*)d_out;

    unsigned short* Ws    = (unsigned short*)d_ws;              // 256*1024 bf16 (frag order)
    unsigned short* hs    = Ws + DOUT * DIN;                    // 4096*256 bf16 (frag order)
    float*          sq    = (float*)(hs + NROWS * DOUT);        // 4096
    unsigned int*   pmaxk = (unsigned int*)(sq + NROWS);        // 4096 keys
    unsigned int*   pmink = pmaxk + NROWS;                      // 4096 keys

    setup<<<16 * 32 * 64 / 256, 256, 0, stream>>>(W, Ws, sq, pmaxk, pmink, out);
    gemm1_direct<<<NROWS / 16, 1024, 0, stream>>>(x, Ws, b, hs, sq);
    hardest_tri<<<NPAIR, 256, 0, stream>>>(hs, sq, targets, pmaxk, pmink);
    finalize<<<NROWS / 256, 256, 0, stream>>>(sq, pmaxk, pmink, out);
}